// Round 8
// baseline (288.905 us; speedup 1.0000x reference)
//
#include <hip/hip_runtime.h>

// ---------- bf16 helpers (raw ushort representation) ----------
__device__ __forceinline__ float bf2f(ushort u) {
    union { uint i; float f; } c; c.i = ((uint)u) << 16; return c.f;
}
__device__ __forceinline__ float bf2lo(uint v) {
    union { uint i; float f; } c; c.i = v << 16; return c.f;
}
__device__ __forceinline__ float bf2hi(uint v) {
    union { uint i; float f; } c; c.i = v & 0xffff0000u; return c.f;
}
__device__ __forceinline__ ushort f2bf(float f) {
    union { float f; uint i; } c; c.f = f;
    uint b = c.i;
    uint r = (b + 0x7fffu + ((b >> 16) & 1u)) >> 16;
    return (ushort)r;
}

typedef __bf16 v8bf __attribute__((ext_vector_type(8)));
typedef float  v4f  __attribute__((ext_vector_type(4)));

__device__ __forceinline__ ushort load_conv(const void* src, int i, int isf32) {
    return isf32 ? f2bf(((const float*)src)[i]) : ((const ushort*)src)[i];
}

// ---------- phase A: per-block dtype sniff + convert x + weight prep + zero deg/pooled ----------
struct SmallSrcs { const void* p[8]; };
// small offsets: lin_b0 0, agg_b0 128, lin_b1 256, agg_b1 384, mp_w1 512, mp_b1 16896, mp_w2 17024, mp_b2 17280 (end 17282)
__global__ __launch_bounds__(256) void phaseA(
    const void* __restrict__ x, ushort* __restrict__ xb, int nx, int nbconv,
    const void* __restrict__ w0, const void* __restrict__ wa0,
    const void* __restrict__ w1, const void* __restrict__ wa1,
    ushort* __restrict__ t0, ushort* __restrict__ ta0,
    ushort* __restrict__ t1, ushort* __restrict__ ta1,
    SmallSrcs s, ushort* __restrict__ smalldst,
    int* __restrict__ deg, int* __restrict__ pooled, int N, int G,
    int* __restrict__ flagOut) {
    __shared__ int sred[256];
    int b = blockIdx.x, t = threadIdx.x;
    // per-block sniff: f32 data -> low u16 decoded as bf16 has wild exponent ~44% of the time
    {
        const uint* words = (const uint*)x;
        int bad = 0;
        for (int i = t; i < 2048; i += 256) {
            uint w = words[i];
            uint exp = (w >> 7) & 0xffu;
            if (exp >= 143u) bad++;
        }
        sred[t] = bad;
        __syncthreads();
        for (int o = 128; o; o >>= 1) {
            if (t < o) sred[t] += sred[t + o];
            __syncthreads();
        }
    }
    const int isf = sred[0] > 64 ? 1 : 0;
    if (b == 0 && t == 0) *flagOut = isf;

    if (b < nbconv) {
        int idx = b * 256 + t;
        int base = idx * 8;
        if (base + 8 <= nx) {
            if (isf) {
                const float4* s4 = (const float4*)x;
                float4 a = s4[idx * 2], bb = s4[idx * 2 + 1];
                union { ushort u[8]; uint4 v; } o;
                o.u[0] = f2bf(a.x); o.u[1] = f2bf(a.y); o.u[2] = f2bf(a.z); o.u[3] = f2bf(a.w);
                o.u[4] = f2bf(bb.x); o.u[5] = f2bf(bb.y); o.u[6] = f2bf(bb.z); o.u[7] = f2bf(bb.w);
                *(uint4*)(xb + base) = o.v;
            } else {
                *(uint4*)(xb + base) = ((const uint4*)x)[idx];
            }
        } else {
            for (int i = base; i < nx; i++) xb[i] = load_conv(x, i, isf);
        }
    } else if (b < nbconv + 452) {
        int idx = (b - nbconv) * 256 + t;   // 0 .. 115585
        if (idx < 98304) {
            const void* W; ushort* T; int K; int local;
            if (idx < 16384)      { W = w0;  T = t0;  K = 128; local = idx; }
            else if (idx < 49152) { W = wa0; T = ta0; K = 256; local = idx - 16384; }
            else if (idx < 65536) { W = w1;  T = t1;  K = 128; local = idx - 49152; }
            else                  { W = wa1; T = ta1; K = 256; local = idx - 65536; }
            ushort v = load_conv(W, local, isf);
            int k = local >> 7;       // row in W
            int n = local & 127;      // col in W
            T[(size_t)n * K + k] = v;
        } else {
            int si = idx - 98304;
            if (si < 17282) {
                const int offs[9] = {0, 128, 256, 384, 512, 16896, 17024, 17280, 17282};
                int seg = 0;
                while (si >= offs[seg + 1]) seg++;
                smalldst[si] = load_conv(s.p[seg], si - offs[seg], isf);
            }
        }
    } else {
        int idx = (b - nbconv - 452) * 256 + t;
        int nd4 = N >> 2;
        int4 z = {0, 0, 0, 0};
        if (idx < nd4) ((int4*)deg)[idx] = z;
        else if (idx == nd4) { for (int i = nd4 * 4; i < N; i++) deg[i] = 0; }
        else if (idx - nd4 - 1 < G * 32) ((int4*)pooled)[idx - nd4 - 1] = z;
    }
}

// ---------- CSR build ----------
__global__ __launch_bounds__(256) void count_deg(const int* __restrict__ dst, int* __restrict__ deg, int E) {
    int i = blockIdx.x * 256 + threadIdx.x;
    if (i < E) atomicAdd(&deg[dst[i]], 1);
}

#define SCAN_CHUNK 1024

__global__ __launch_bounds__(256) void chunk_sum_kernel(const int* __restrict__ deg,
                                                        int* __restrict__ csums, int n) {
    __shared__ int s[256];
    int t = threadIdx.x;
    int base = blockIdx.x * SCAN_CHUNK + t * 4;
    int v = 0;
    if (base + 4 <= n) {
        int4 q = *(const int4*)(deg + base);
        v = q.x + q.y + q.z + q.w;
    } else {
        for (int i = base; i < n; i++) v += deg[i];
    }
    s[t] = v;
    __syncthreads();
    for (int o = 128; o; o >>= 1) {
        if (t < o) s[t] += s[t + o];
        __syncthreads();
    }
    if (t == 0) csums[blockIdx.x] = s[0];
}

__global__ __launch_bounds__(256) void scan_phase2(const int* __restrict__ deg,
                                                   const int* __restrict__ csums,
                                                   int* __restrict__ rowptr, int* __restrict__ cursor,
                                                   int n) {
    __shared__ int red[256];
    int t = threadIdx.x, b = blockIdx.x;
    int v = 0;
    for (int i = t; i < b; i += 256) v += csums[i];
    red[t] = v;
    __syncthreads();
    for (int o = 128; o; o >>= 1) {
        if (t < o) red[t] += red[t + o];
        __syncthreads();
    }
    int chunkOff = red[0];
    __syncthreads();
    int base = b * SCAN_CHUNK + t * 4;
    int d0 = 0, d1 = 0, d2 = 0, d3 = 0;
    if (base + 4 <= n) {
        int4 q = *(const int4*)(deg + base);
        d0 = q.x; d1 = q.y; d2 = q.z; d3 = q.w;
    } else {
        if (base < n)     d0 = deg[base];
        if (base + 1 < n) d1 = deg[base + 1];
        if (base + 2 < n) d2 = deg[base + 2];
        if (base + 3 < n) d3 = deg[base + 3];
    }
    int s4 = d0 + d1 + d2 + d3;
    red[t] = s4;
    __syncthreads();
    for (int o = 1; o < 256; o <<= 1) {
        int u = (t >= o) ? red[t - o] : 0;
        __syncthreads();
        red[t] += u;
        __syncthreads();
    }
    int run = chunkOff + red[t] - s4;  // exclusive prefix at base
    if (base < n)     { rowptr[base]     = run; cursor[base]     = run; run += d0; }
    if (base + 1 < n) { rowptr[base + 1] = run; cursor[base + 1] = run; run += d1; }
    if (base + 2 < n) { rowptr[base + 2] = run; cursor[base + 2] = run; run += d2; }
    if (base + 3 < n) { rowptr[base + 3] = run; cursor[base + 3] = run; run += d3; }
    if (n >= base && n < base + 4) rowptr[n] = run;  // exactly one thread grid-wide
}

__global__ __launch_bounds__(256) void fill_kernel(const int* __restrict__ src, const int* __restrict__ dst,
                                                   int* __restrict__ cursor, int* __restrict__ csr_src, int E) {
    int i = blockIdx.x * 256 + threadIdx.x;
    if (i < E) {
        int pos = atomicAdd(&cursor[dst[i]], 1);
        csr_src[pos] = src[i];
    }
}

// ---------- MFMA GEMM, full-128-K staging per round ----------
// C = relu(A @ Bt^T + bias) [+ row-L2-normalize if NORM]
//   AGG:  stage-0 A tile is computed in-kernel: mean of msgsrc rows per CSR (fused aggregate)
//   POOL: fused segment-max into pooled (no C store)
//   FUSE: after phase 1, Mout = relu(H @ Bt2^T + bias2) with H kept in LDS
template <int NSTAGE, bool NORM, bool POOL, bool FUSE, bool AGG>
__global__ __launch_bounds__(256) void gemm_kernel(
    const ushort* __restrict__ A0, const ushort* __restrict__ A1,
    const ushort* __restrict__ Bt, const ushort* __restrict__ bias,
    ushort* __restrict__ Cout, int M,
    const int* __restrict__ batchv, int* __restrict__ pooled,
    const ushort* __restrict__ Bt2, const ushort* __restrict__ bias2,
    ushort* __restrict__ Mout,
    const int* __restrict__ rowptr, const int* __restrict__ csr_src,
    const ushort* __restrict__ msgsrc) {
    __shared__ __bf16 AsT[128 * 136];   // 34.8 KB  (reused as H tile in FUSE phase 2)
    __shared__ __bf16 BsT[128 * 136];   // 34.8 KB  (reused as Bt2 tile in FUSE phase 2)
    __shared__ int PoolLoc[POOL ? 8 * 128 : 1];
    const int t = threadIdx.x;
    const int w = t >> 6, lane = t & 63, ln = lane & 15, q = lane >> 4;
    const int blockRow = blockIdx.x * 128;
    const int K = NSTAGE * 128;

    if (POOL) {
        for (int i = t; i < 8 * 128; i += 256) PoolLoc[i] = 0;
    }

    v4f acc[2][8];
#pragma unroll
    for (int i = 0; i < 2; i++)
#pragma unroll
        for (int j = 0; j < 8; j++) acc[i][j] = (v4f){0.f, 0.f, 0.f, 0.f};

#pragma unroll
    for (int st = 0; st < NSTAGE; st++) {
        // B staging (always from global, full 128x128)
#pragma unroll
        for (int i = 0; i < 8; i++) {
            int c = i * 256 + t;
            int row = c >> 4, k8 = (c & 15) * 8;
            *(uint4*)&BsT[row * 136 + k8] = *(const uint4*)(Bt + (size_t)row * K + st * 128 + k8);
        }
        if (AGG && st == 0) {
            // fused aggregate: 16 lanes per node, 16 groups, 8 passes over 128 nodes
            int grp = t >> 4, l16 = t & 15;
#pragma unroll
            for (int pass = 0; pass < 8; pass++) {
                int nn = pass * 16 + grp;
                int node = blockRow + nn; if (node >= M) node = M - 1;
                int start = rowptr[node], end = rowptr[node + 1];
                float a[8] = {0.f, 0.f, 0.f, 0.f, 0.f, 0.f, 0.f, 0.f};
#pragma unroll 4
                for (int j = start; j < end; j++) {
                    int s = csr_src[j];
                    uint4 v = *(const uint4*)(msgsrc + (size_t)s * 128 + l16 * 8);
                    a[0] += bf2lo(v.x); a[1] += bf2hi(v.x);
                    a[2] += bf2lo(v.y); a[3] += bf2hi(v.y);
                    a[4] += bf2lo(v.z); a[5] += bf2hi(v.z);
                    a[6] += bf2lo(v.w); a[7] += bf2hi(v.w);
                }
                float inv = 1.0f / fmaxf((float)(end - start), 1.0f);
                union { ushort u[8]; uint4 v; } o;
#pragma unroll
                for (int i = 0; i < 8; i++) o.u[i] = f2bf(a[i] * inv);
                *(uint4*)&AsT[nn * 136 + l16 * 8] = o.v;
            }
        } else {
            const ushort* Ap = st ? A1 : A0;
#pragma unroll
            for (int i = 0; i < 8; i++) {
                int c = i * 256 + t;
                int row = c >> 4, k8 = (c & 15) * 8;
                int grow = blockRow + row; if (grow >= M) grow = M - 1;
                *(uint4*)&AsT[row * 136 + k8] = *(const uint4*)(Ap + (size_t)grow * 128 + k8);
            }
        }
        __syncthreads();
#pragma unroll
        for (int k0 = 0; k0 < 128; k0 += 32) {
            v8bf a0 = *(const v8bf*)&AsT[(w * 32 + ln) * 136 + k0 + q * 8];
            v8bf a1 = *(const v8bf*)&AsT[(w * 32 + 16 + ln) * 136 + k0 + q * 8];
#pragma unroll
            for (int nt = 0; nt < 8; nt++) {
                v8bf b = *(const v8bf*)&BsT[(nt * 16 + ln) * 136 + k0 + q * 8];
                acc[0][nt] = __builtin_amdgcn_mfma_f32_16x16x32_bf16(a0, b, acc[0][nt], 0, 0, 0);
                acc[1][nt] = __builtin_amdgcn_mfma_f32_16x16x32_bf16(a1, b, acc[1][nt], 0, 0, 0);
            }
        }
        __syncthreads();
    }

    float biasf[8];
#pragma unroll
    for (int nt = 0; nt < 8; nt++) biasf[nt] = bf2f(bias[nt * 16 + ln]);

    const int minB = POOL ? batchv[blockRow < M ? blockRow : M - 1] : 0;
    ushort* HsU = (ushort*)AsT;   // FUSE phase-2 A tile (128 x 136); safe: phase-1 staging done

#pragma unroll
    for (int mt = 0; mt < 2; mt++) {
        float v[8][4];
#pragma unroll
        for (int nt = 0; nt < 8; nt++)
#pragma unroll
            for (int r = 0; r < 4; r++) {
                float x = acc[mt][nt][r] + biasf[nt];
                v[nt][r] = x > 0.f ? x : 0.f;
            }
        float inv[4];
        if (NORM) {
#pragma unroll
            for (int r = 0; r < 4; r++) {
                float p = 0.f;
#pragma unroll
                for (int nt = 0; nt < 8; nt++) p += v[nt][r] * v[nt][r];
                p += __shfl_xor(p, 1);
                p += __shfl_xor(p, 2);
                p += __shfl_xor(p, 4);
                p += __shfl_xor(p, 8);
                inv[r] = 1.0f / fmaxf(sqrtf(p), 1e-12f);
            }
        }
        int rowloc = w * 32 + mt * 16 + q * 4;
#pragma unroll
        for (int r = 0; r < 4; r++) {
            int grow = blockRow + rowloc + r;
            if (POOL) {
                if (grow < M) {
                    int b = batchv[grow];
                    int rel = b - minB;
#pragma unroll
                    for (int nt = 0; nt < 8; nt++) {
                        float x = v[nt][r] * inv[r];
                        int xi = __float_as_int(x);
                        if (rel < 8) atomicMax(&PoolLoc[rel * 128 + nt * 16 + ln], xi);
                        else         atomicMax(&pooled[b * 128 + nt * 16 + ln], xi);
                    }
                }
            } else {
#pragma unroll
                for (int nt = 0; nt < 8; nt++) {
                    float x = NORM ? v[nt][r] * inv[r] : v[nt][r];
                    ushort xb = f2bf(x);
                    if (grow < M) Cout[(size_t)grow * 128 + nt * 16 + ln] = xb;
                    if (FUSE) HsU[(rowloc + r) * 136 + nt * 16 + ln] = xb;
                }
            }
        }
    }

    if (POOL) {
        __syncthreads();
        int lastRow = blockRow + 127; if (lastRow >= M) lastRow = M - 1;
        int span = batchv[lastRow] - minB + 1;
        if (span > 8) span = 8;
        for (int i = t; i < span * 128; i += 256) {
            int vv = PoolLoc[i];
            if (vv != 0) atomicMax(&pooled[(minB + (i >> 7)) * 128 + (i & 127)], vv);
        }
    }

    if (FUSE) {
        // phase 2: Mout = relu(H @ Bt2^T + bias2); H in AsT, Bt2 staged fully into BsT
#pragma unroll
        for (int i = 0; i < 8; i++) {
            int c = i * 256 + t;
            int row = c >> 4, k8 = (c & 15) * 8;
            *(uint4*)&BsT[row * 136 + k8] = *(const uint4*)(Bt2 + (size_t)row * 128 + k8);
        }
        __syncthreads();

        v4f acc2[2][8];
#pragma unroll
        for (int i = 0; i < 2; i++)
#pragma unroll
            for (int j = 0; j < 8; j++) acc2[i][j] = (v4f){0.f, 0.f, 0.f, 0.f};

#pragma unroll
        for (int k0 = 0; k0 < 128; k0 += 32) {
            v8bf a0 = *(const v8bf*)&AsT[(w * 32 + ln) * 136 + k0 + q * 8];
            v8bf a1 = *(const v8bf*)&AsT[(w * 32 + 16 + ln) * 136 + k0 + q * 8];
#pragma unroll
            for (int nt = 0; nt < 8; nt++) {
                v8bf b = *(const v8bf*)&BsT[(nt * 16 + ln) * 136 + k0 + q * 8];
                acc2[0][nt] = __builtin_amdgcn_mfma_f32_16x16x32_bf16(a0, b, acc2[0][nt], 0, 0, 0);
                acc2[1][nt] = __builtin_amdgcn_mfma_f32_16x16x32_bf16(a1, b, acc2[1][nt], 0, 0, 0);
            }
        }

        float biasf2[8];
#pragma unroll
        for (int nt = 0; nt < 8; nt++) biasf2[nt] = bf2f(bias2[nt * 16 + ln]);
#pragma unroll
        for (int mt = 0; mt < 2; mt++) {
            int rowbase = blockRow + w * 32 + mt * 16 + q * 4;
#pragma unroll
            for (int r = 0; r < 4; r++) {
                int grow = rowbase + r;
                if (grow < M) {
#pragma unroll
                    for (int nt = 0; nt < 8; nt++) {
                        float x = acc2[mt][nt][r] + biasf2[nt];
                        Mout[(size_t)grow * 128 + nt * 16 + ln] = f2bf(x > 0.f ? x : 0.f);
                    }
                }
            }
        }
    }
}

// ---------- MLP head + log_softmax: one block per graph ----------
__global__ __launch_bounds__(256) void final_kernel(const float* __restrict__ pooled,
                                                    const ushort* __restrict__ small,
                                                    void* __restrict__ out, int G,
                                                    const int* __restrict__ flag) {
    __shared__ float P[128];
    __shared__ float Thalf[128];
    __shared__ float T[128];
    __shared__ float R0[128], R1[128];
    const ushort* w1 = small + 512;
    const ushort* b1 = small + 16896;
    const ushort* w2 = small + 17024;
    const ushort* b2 = small + 17280;
    int g = blockIdx.x;
    int t = threadIdx.x;
    int j = t & 127, half = t >> 7;
    if (t < 128) P[t] = pooled[g * 128 + t];
    __syncthreads();
    float acc = 0.f;
    int k0 = half * 64;
#pragma unroll 8
    for (int k = k0; k < k0 + 64; k++) acc += P[k] * bf2f(w1[k * 128 + j]);
    if (half == 0) Thalf[j] = acc;
    __syncthreads();
    if (half == 1) T[j] = Thalf[j] + acc + bf2f(b1[j]);
    __syncthreads();
    if (t < 128) {
        float tv = T[t];
        R0[t] = tv * bf2f(w2[t * 2]);
        R1[t] = tv * bf2f(w2[t * 2 + 1]);
    }
    __syncthreads();
    for (int o = 64; o; o >>= 1) {
        if (t < o) { R0[t] += R0[t + o]; R1[t] += R1[t + o]; }
        __syncthreads();
    }
    if (t == 0) {
        float z0 = R0[0] + bf2f(b2[0]);
        float z1 = R1[0] + bf2f(b2[1]);
        float m = fmaxf(z0, z1);
        float l = m + logf(expf(z0 - m) + expf(z1 - m));
        float o0 = z0 - l, o1 = z1 - l;
        if (*flag) {
            ((float*)out)[2 * g]     = o0;
            ((float*)out)[2 * g + 1] = o1;
        } else {
            ((ushort*)out)[2 * g]     = f2bf(o0);
            ((ushort*)out)[2 * g + 1] = f2bf(o1);
        }
    }
}

extern "C" void kernel_launch(void* const* d_in, const int* in_sizes, int n_in,
                              void* d_out, int out_size, void* d_ws, size_t ws_size,
                              hipStream_t stream) {
    const void* x      = d_in[0];
    const int*  ei     = (const int*)d_in[1];
    const int*  batch  = (const int*)d_in[2];

    const int N = in_sizes[0] / 128;   // 50000 nodes
    const int E = in_sizes[1] / 2;     // 600000 edges
    const int G = out_size / 2;        // 64 graphs
    const int* srcIdx = ei;
    const int* dstIdx = ei + E;

    char* ws = (char*)d_ws;
    size_t off = 0;
    auto alloc = [&](size_t bytes) -> void* {
        off = (off + 255) & ~(size_t)255;
        void* p = ws + off;
        off += bytes;
        return p;
    };
    int*    flag    = (int*)alloc(4);
    int*    deg     = (int*)alloc((size_t)N * 4);
    int*    rowptr  = (int*)alloc((size_t)(N + 1) * 4);
    int*    cursor  = (int*)alloc((size_t)N * 4);
    int*    csr_src = (int*)alloc((size_t)E * 4);
    int*    csums   = (int*)alloc(((size_t)N / SCAN_CHUNK + 2) * 4);
    ushort* Wt0     = (ushort*)alloc(128 * 128 * 2);
    ushort* WtA0    = (ushort*)alloc(256 * 128 * 2);
    ushort* Wt1     = (ushort*)alloc(128 * 128 * 2);
    ushort* WtA1    = (ushort*)alloc(256 * 128 * 2);
    ushort* small   = (ushort*)alloc(17282 * 2);
    ushort* xb      = (ushort*)alloc((size_t)N * 128 * 2);
    ushort* msgA    = (ushort*)alloc((size_t)N * 128 * 2);
    ushort* msgB    = (ushort*)alloc((size_t)N * 128 * 2);
    ushort* h0      = (ushort*)alloc((size_t)N * 128 * 2);
    int*    pooled  = (int*)alloc((size_t)G * 128 * 4);

    // phase A: sniff (per-block) + convert x + weight prep + zero deg/pooled
    SmallSrcs ss;
    ss.p[0] = d_in[4];  ss.p[1] = d_in[6];  ss.p[2] = d_in[8];  ss.p[3] = d_in[10];
    ss.p[4] = d_in[11]; ss.p[5] = d_in[12]; ss.p[6] = d_in[13]; ss.p[7] = d_in[14];
    int nbconv = (N * 128 + 2047) / 2048;
    int nbzero = ((N / 4 + 1 + G * 32) + 255) / 256;
    phaseA<<<nbconv + 452 + nbzero, 256, 0, stream>>>(
        x, xb, N * 128, nbconv,
        d_in[3], d_in[5], d_in[7], d_in[9],
        Wt0, WtA0, Wt1, WtA1, ss, small, deg, pooled, N, G, flag);

    int gb = (N + 127) / 128;
    int eb = (E + 255) / 256;

    // layer-0 lin GEMM (independent of CSR) -> msgA
    gemm_kernel<1, false, false, false, false><<<gb, 256, 0, stream>>>(
        xb, xb, Wt0, small + 0, msgA, N, nullptr, nullptr, nullptr, nullptr, nullptr,
        nullptr, nullptr, nullptr);

    // CSR build
    count_deg<<<eb, 256, 0, stream>>>(dstIdx, deg, E);
    int nchunks = (N + SCAN_CHUNK - 1) / SCAN_CHUNK;
    chunk_sum_kernel<<<nchunks, 256, 0, stream>>>(deg, csums, N);
    scan_phase2<<<N / SCAN_CHUNK + 1, 256, 0, stream>>>(deg, csums, rowptr, cursor, N);
    fill_kernel<<<eb, 256, 0, stream>>>(srcIdx, dstIdx, cursor, csr_src, E);

    // layer 0: fused (aggregate msgA) + upd0 -> h0, + lin1 -> msgB
    gemm_kernel<2, true, false, true, true><<<gb, 256, 0, stream>>>(
        nullptr, xb, WtA0, small + 128, h0, N, nullptr, nullptr, Wt1, small + 256, msgB,
        rowptr, csr_src, msgA);

    // layer 1: fused (aggregate msgB) + upd1 + max-pool
    gemm_kernel<2, true, true, false, true><<<gb, 256, 0, stream>>>(
        nullptr, h0, WtA1, small + 384, nullptr, N, batch, pooled, nullptr, nullptr, nullptr,
        rowptr, csr_src, msgB);

    // head
    final_kernel<<<G, 256, 0, stream>>>((const float*)pooled, small, d_out, G, flag);
}

// Round 9
// 281.244 us; speedup vs baseline: 1.0272x; 1.0272x over previous
//
#include <hip/hip_runtime.h>

// ---------- bf16 helpers (raw ushort representation) ----------
__device__ __forceinline__ float bf2f(ushort u) {
    union { uint i; float f; } c; c.i = ((uint)u) << 16; return c.f;
}
__device__ __forceinline__ float bf2lo(uint v) {
    union { uint i; float f; } c; c.i = v << 16; return c.f;
}
__device__ __forceinline__ float bf2hi(uint v) {
    union { uint i; float f; } c; c.i = v & 0xffff0000u; return c.f;
}
__device__ __forceinline__ ushort f2bf(float f) {
    union { float f; uint i; } c; c.f = f;
    uint b = c.i;
    uint r = (b + 0x7fffu + ((b >> 16) & 1u)) >> 16;
    return (ushort)r;
}

typedef __bf16 v8bf __attribute__((ext_vector_type(8)));
typedef float  v4f  __attribute__((ext_vector_type(4)));

__device__ __forceinline__ ushort load_conv(const void* src, int i, int isf32) {
    return isf32 ? f2bf(((const float*)src)[i]) : ((const ushort*)src)[i];
}

// ---------- phase A: per-block dtype sniff + convert x + weight prep + zero deg/pooled ----------
struct SmallSrcs { const void* p[8]; };
// small offsets: lin_b0 0, agg_b0 128, lin_b1 256, agg_b1 384, mp_w1 512, mp_b1 16896, mp_w2 17024, mp_b2 17280 (end 17282)
__global__ __launch_bounds__(256) void phaseA(
    const void* __restrict__ x, ushort* __restrict__ xb, int nx, int nbconv,
    const void* __restrict__ w0, const void* __restrict__ wa0,
    const void* __restrict__ w1, const void* __restrict__ wa1,
    ushort* __restrict__ t0, ushort* __restrict__ ta0,
    ushort* __restrict__ t1, ushort* __restrict__ ta1,
    SmallSrcs s, ushort* __restrict__ smalldst,
    int* __restrict__ deg, int* __restrict__ pooled, int N, int G,
    int* __restrict__ flagOut) {
    __shared__ int sred[256];
    int b = blockIdx.x, t = threadIdx.x;
    // per-block sniff: f32 data -> low u16 decoded as bf16 has wild exponent ~44% of the time
    {
        const uint* words = (const uint*)x;
        int bad = 0;
        for (int i = t; i < 2048; i += 256) {
            uint w = words[i];
            uint exp = (w >> 7) & 0xffu;
            if (exp >= 143u) bad++;
        }
        sred[t] = bad;
        __syncthreads();
        for (int o = 128; o; o >>= 1) {
            if (t < o) sred[t] += sred[t + o];
            __syncthreads();
        }
    }
    const int isf = sred[0] > 64 ? 1 : 0;
    if (b == 0 && t == 0) *flagOut = isf;

    if (b < nbconv) {
        int idx = b * 256 + t;
        int base = idx * 8;
        if (base + 8 <= nx) {
            if (isf) {
                const float4* s4 = (const float4*)x;
                float4 a = s4[idx * 2], bb = s4[idx * 2 + 1];
                union { ushort u[8]; uint4 v; } o;
                o.u[0] = f2bf(a.x); o.u[1] = f2bf(a.y); o.u[2] = f2bf(a.z); o.u[3] = f2bf(a.w);
                o.u[4] = f2bf(bb.x); o.u[5] = f2bf(bb.y); o.u[6] = f2bf(bb.z); o.u[7] = f2bf(bb.w);
                *(uint4*)(xb + base) = o.v;
            } else {
                *(uint4*)(xb + base) = ((const uint4*)x)[idx];
            }
        } else {
            for (int i = base; i < nx; i++) xb[i] = load_conv(x, i, isf);
        }
    } else if (b < nbconv + 452) {
        int idx = (b - nbconv) * 256 + t;   // 0 .. 115585
        if (idx < 98304) {
            const void* W; ushort* T; int K; int local;
            if (idx < 16384)      { W = w0;  T = t0;  K = 128; local = idx; }
            else if (idx < 49152) { W = wa0; T = ta0; K = 256; local = idx - 16384; }
            else if (idx < 65536) { W = w1;  T = t1;  K = 128; local = idx - 49152; }
            else                  { W = wa1; T = ta1; K = 256; local = idx - 65536; }
            ushort v = load_conv(W, local, isf);
            int k = local >> 7;       // row in W
            int n = local & 127;      // col in W
            T[(size_t)n * K + k] = v;
        } else {
            int si = idx - 98304;
            if (si < 17282) {
                const int offs[9] = {0, 128, 256, 384, 512, 16896, 17024, 17280, 17282};
                int seg = 0;
                while (si >= offs[seg + 1]) seg++;
                smalldst[si] = load_conv(s.p[seg], si - offs[seg], isf);
            }
        }
    } else {
        int idx = (b - nbconv - 452) * 256 + t;
        int nd4 = N >> 2;
        int4 z = {0, 0, 0, 0};
        if (idx < nd4) ((int4*)deg)[idx] = z;
        else if (idx == nd4) { for (int i = nd4 * 4; i < N; i++) deg[i] = 0; }
        else if (idx - nd4 - 1 < G * 32) ((int4*)pooled)[idx - nd4 - 1] = z;
    }
}

// ---------- CSR build ----------
__global__ __launch_bounds__(256) void count_deg(const int* __restrict__ dst, int* __restrict__ deg, int E) {
    int i = blockIdx.x * 256 + threadIdx.x;
    if (i < E) atomicAdd(&deg[dst[i]], 1);
}

#define SCAN_CHUNK 1024

__global__ __launch_bounds__(256) void chunk_sum_kernel(const int* __restrict__ deg,
                                                        int* __restrict__ csums, int n) {
    __shared__ int s[256];
    int t = threadIdx.x;
    int base = blockIdx.x * SCAN_CHUNK + t * 4;
    int v = 0;
    if (base + 4 <= n) {
        int4 q = *(const int4*)(deg + base);
        v = q.x + q.y + q.z + q.w;
    } else {
        for (int i = base; i < n; i++) v += deg[i];
    }
    s[t] = v;
    __syncthreads();
    for (int o = 128; o; o >>= 1) {
        if (t < o) s[t] += s[t + o];
        __syncthreads();
    }
    if (t == 0) csums[blockIdx.x] = s[0];
}

__global__ __launch_bounds__(256) void scan_phase2(const int* __restrict__ deg,
                                                   const int* __restrict__ csums,
                                                   int* __restrict__ rowptr, int* __restrict__ cursor,
                                                   int n) {
    __shared__ int red[256];
    int t = threadIdx.x, b = blockIdx.x;
    int v = 0;
    for (int i = t; i < b; i += 256) v += csums[i];
    red[t] = v;
    __syncthreads();
    for (int o = 128; o; o >>= 1) {
        if (t < o) red[t] += red[t + o];
        __syncthreads();
    }
    int chunkOff = red[0];
    __syncthreads();
    int base = b * SCAN_CHUNK + t * 4;
    int d0 = 0, d1 = 0, d2 = 0, d3 = 0;
    if (base + 4 <= n) {
        int4 q = *(const int4*)(deg + base);
        d0 = q.x; d1 = q.y; d2 = q.z; d3 = q.w;
    } else {
        if (base < n)     d0 = deg[base];
        if (base + 1 < n) d1 = deg[base + 1];
        if (base + 2 < n) d2 = deg[base + 2];
        if (base + 3 < n) d3 = deg[base + 3];
    }
    int s4 = d0 + d1 + d2 + d3;
    red[t] = s4;
    __syncthreads();
    for (int o = 1; o < 256; o <<= 1) {
        int u = (t >= o) ? red[t - o] : 0;
        __syncthreads();
        red[t] += u;
        __syncthreads();
    }
    int run = chunkOff + red[t] - s4;  // exclusive prefix at base
    if (base < n)     { rowptr[base]     = run; cursor[base]     = run; run += d0; }
    if (base + 1 < n) { rowptr[base + 1] = run; cursor[base + 1] = run; run += d1; }
    if (base + 2 < n) { rowptr[base + 2] = run; cursor[base + 2] = run; run += d2; }
    if (base + 3 < n) { rowptr[base + 3] = run; cursor[base + 3] = run; run += d3; }
    if (n >= base && n < base + 4) rowptr[n] = run;  // exactly one thread grid-wide
}

__global__ __launch_bounds__(256) void fill_kernel(const int* __restrict__ src, const int* __restrict__ dst,
                                                   int* __restrict__ cursor, int* __restrict__ csr_src, int E) {
    int i = blockIdx.x * 256 + threadIdx.x;
    if (i < E) {
        int pos = atomicAdd(&cursor[dst[i]], 1);
        csr_src[pos] = src[i];
    }
}

// ---------- MFMA GEMM, full-128-K staging per round ----------
// C = relu(A @ Bt^T + bias) [+ row-L2-normalize if NORM]
//   POOL: fused segment-max into pooled (no C store)
//   FUSE: after phase 1, Mout = relu(H @ Bt2^T + bias2) with H kept in LDS
template <int NSTAGE, bool NORM, bool POOL, bool FUSE>
__global__ __launch_bounds__(256) void gemm_kernel(
    const ushort* __restrict__ A0, const ushort* __restrict__ A1,
    const ushort* __restrict__ Bt, const ushort* __restrict__ bias,
    ushort* __restrict__ Cout, int M,
    const int* __restrict__ batchv, int* __restrict__ pooled,
    const ushort* __restrict__ Bt2, const ushort* __restrict__ bias2,
    ushort* __restrict__ Mout) {
    __shared__ __bf16 AsT[128 * 136];   // 34.8 KB  (reused as H tile in FUSE phase 2)
    __shared__ __bf16 BsT[128 * 136];   // 34.8 KB  (reused as Bt2 tile in FUSE phase 2)
    __shared__ int PoolLoc[POOL ? 8 * 128 : 1];
    const int t = threadIdx.x;
    const int w = t >> 6, lane = t & 63, ln = lane & 15, q = lane >> 4;
    const int blockRow = blockIdx.x * 128;
    const int K = NSTAGE * 128;

    if (POOL) {
        for (int i = t; i < 8 * 128; i += 256) PoolLoc[i] = 0;
    }

    v4f acc[2][8];
#pragma unroll
    for (int i = 0; i < 2; i++)
#pragma unroll
        for (int j = 0; j < 8; j++) acc[i][j] = (v4f){0.f, 0.f, 0.f, 0.f};

#pragma unroll
    for (int st = 0; st < NSTAGE; st++) {
        const ushort* Ap = st ? A1 : A0;
#pragma unroll
        for (int i = 0; i < 8; i++) {
            int c = i * 256 + t;
            int row = c >> 4, k8 = (c & 15) * 8;
            int grow = blockRow + row; if (grow >= M) grow = M - 1;
            *(uint4*)&AsT[row * 136 + k8] = *(const uint4*)(Ap + (size_t)grow * 128 + k8);
            *(uint4*)&BsT[row * 136 + k8] = *(const uint4*)(Bt + (size_t)row * K + st * 128 + k8);
        }
        __syncthreads();
#pragma unroll
        for (int k0 = 0; k0 < 128; k0 += 32) {
            v8bf a0 = *(const v8bf*)&AsT[(w * 32 + ln) * 136 + k0 + q * 8];
            v8bf a1 = *(const v8bf*)&AsT[(w * 32 + 16 + ln) * 136 + k0 + q * 8];
#pragma unroll
            for (int nt = 0; nt < 8; nt++) {
                v8bf b = *(const v8bf*)&BsT[(nt * 16 + ln) * 136 + k0 + q * 8];
                acc[0][nt] = __builtin_amdgcn_mfma_f32_16x16x32_bf16(a0, b, acc[0][nt], 0, 0, 0);
                acc[1][nt] = __builtin_amdgcn_mfma_f32_16x16x32_bf16(a1, b, acc[1][nt], 0, 0, 0);
            }
        }
        __syncthreads();
    }

    float biasf[8];
#pragma unroll
    for (int nt = 0; nt < 8; nt++) biasf[nt] = bf2f(bias[nt * 16 + ln]);

    const int minB = POOL ? batchv[blockRow < M ? blockRow : M - 1] : 0;
    ushort* HsU = (ushort*)AsT;   // FUSE phase-2 A tile (128 x 136); safe: phase-1 staging done

#pragma unroll
    for (int mt = 0; mt < 2; mt++) {
        float v[8][4];
#pragma unroll
        for (int nt = 0; nt < 8; nt++)
#pragma unroll
            for (int r = 0; r < 4; r++) {
                float x = acc[mt][nt][r] + biasf[nt];
                v[nt][r] = x > 0.f ? x : 0.f;
            }
        float inv[4];
        if (NORM) {
#pragma unroll
            for (int r = 0; r < 4; r++) {
                float p = 0.f;
#pragma unroll
                for (int nt = 0; nt < 8; nt++) p += v[nt][r] * v[nt][r];
                p += __shfl_xor(p, 1);
                p += __shfl_xor(p, 2);
                p += __shfl_xor(p, 4);
                p += __shfl_xor(p, 8);
                inv[r] = 1.0f / fmaxf(sqrtf(p), 1e-12f);
            }
        }
        int rowloc = w * 32 + mt * 16 + q * 4;
#pragma unroll
        for (int r = 0; r < 4; r++) {
            int grow = blockRow + rowloc + r;
            if (POOL) {
                if (grow < M) {
                    int b = batchv[grow];
                    int rel = b - minB;
#pragma unroll
                    for (int nt = 0; nt < 8; nt++) {
                        float x = v[nt][r] * inv[r];
                        int xi = __float_as_int(x);
                        if (rel < 8) atomicMax(&PoolLoc[rel * 128 + nt * 16 + ln], xi);
                        else         atomicMax(&pooled[b * 128 + nt * 16 + ln], xi);
                    }
                }
            } else {
#pragma unroll
                for (int nt = 0; nt < 8; nt++) {
                    float x = NORM ? v[nt][r] * inv[r] : v[nt][r];
                    ushort xb = f2bf(x);
                    if (grow < M) Cout[(size_t)grow * 128 + nt * 16 + ln] = xb;
                    if (FUSE) HsU[(rowloc + r) * 136 + nt * 16 + ln] = xb;
                }
            }
        }
    }

    if (POOL) {
        __syncthreads();
        int lastRow = blockRow + 127; if (lastRow >= M) lastRow = M - 1;
        int span = batchv[lastRow] - minB + 1;
        if (span > 8) span = 8;
        for (int i = t; i < span * 128; i += 256) {
            int vv = PoolLoc[i];
            if (vv != 0) atomicMax(&pooled[(minB + (i >> 7)) * 128 + (i & 127)], vv);
        }
    }

    if (FUSE) {
        // phase 2: Mout = relu(H @ Bt2^T + bias2); H in AsT, Bt2 staged fully into BsT
#pragma unroll
        for (int i = 0; i < 8; i++) {
            int c = i * 256 + t;
            int row = c >> 4, k8 = (c & 15) * 8;
            *(uint4*)&BsT[row * 136 + k8] = *(const uint4*)(Bt2 + (size_t)row * 128 + k8);
        }
        __syncthreads();

        v4f acc2[2][8];
#pragma unroll
        for (int i = 0; i < 2; i++)
#pragma unroll
            for (int j = 0; j < 8; j++) acc2[i][j] = (v4f){0.f, 0.f, 0.f, 0.f};

#pragma unroll
        for (int k0 = 0; k0 < 128; k0 += 32) {
            v8bf a0 = *(const v8bf*)&AsT[(w * 32 + ln) * 136 + k0 + q * 8];
            v8bf a1 = *(const v8bf*)&AsT[(w * 32 + 16 + ln) * 136 + k0 + q * 8];
#pragma unroll
            for (int nt = 0; nt < 8; nt++) {
                v8bf b = *(const v8bf*)&BsT[(nt * 16 + ln) * 136 + k0 + q * 8];
                acc2[0][nt] = __builtin_amdgcn_mfma_f32_16x16x32_bf16(a0, b, acc2[0][nt], 0, 0, 0);
                acc2[1][nt] = __builtin_amdgcn_mfma_f32_16x16x32_bf16(a1, b, acc2[1][nt], 0, 0, 0);
            }
        }

        float biasf2[8];
#pragma unroll
        for (int nt = 0; nt < 8; nt++) biasf2[nt] = bf2f(bias2[nt * 16 + ln]);
#pragma unroll
        for (int mt = 0; mt < 2; mt++) {
            int rowbase = blockRow + w * 32 + mt * 16 + q * 4;
#pragma unroll
            for (int r = 0; r < 4; r++) {
                int grow = rowbase + r;
                if (grow < M) {
#pragma unroll
                    for (int nt = 0; nt < 8; nt++) {
                        float x = acc2[mt][nt][r] + biasf2[nt];
                        Mout[(size_t)grow * 128 + nt * 16 + ln] = f2bf(x > 0.f ? x : 0.f);
                    }
                }
            }
        }
    }
}

// ---------- CSR mean-aggregate: 8 edges in flight per wave, 32B/lane ----------
__global__ __launch_bounds__(256) void aggregate_kernel(
    const ushort* __restrict__ msg, const int* __restrict__ rowptr,
    const int* __restrict__ csr_src, ushort* __restrict__ agg, int n) {
    int wid = (int)((blockIdx.x * 256u + threadIdx.x) >> 6);
    int lane = threadIdx.x & 63;
    int sub = lane >> 3;       // which of 8 concurrent edges
    int l8 = lane & 7;         // 8 lanes x 16 bf16 (32B) cover a 256B row
    if (wid >= n) return;
    int start = rowptr[wid], end = rowptr[wid + 1];
    float a[16];
#pragma unroll
    for (int i = 0; i < 16; i++) a[i] = 0.f;
#pragma unroll 2
    for (int j = start + sub; j < end; j += 8) {
        int s = csr_src[j];
        const uint4* p = (const uint4*)(msg + (size_t)s * 128 + l8 * 16);
        uint4 v0 = p[0], v1 = p[1];
        a[0] += bf2lo(v0.x); a[1] += bf2hi(v0.x);
        a[2] += bf2lo(v0.y); a[3] += bf2hi(v0.y);
        a[4] += bf2lo(v0.z); a[5] += bf2hi(v0.z);
        a[6] += bf2lo(v0.w); a[7] += bf2hi(v0.w);
        a[8]  += bf2lo(v1.x); a[9]  += bf2hi(v1.x);
        a[10] += bf2lo(v1.y); a[11] += bf2hi(v1.y);
        a[12] += bf2lo(v1.z); a[13] += bf2hi(v1.z);
        a[14] += bf2lo(v1.w); a[15] += bf2hi(v1.w);
    }
#pragma unroll
    for (int i = 0; i < 16; i++) {
        a[i] += __shfl_xor(a[i], 8);
        a[i] += __shfl_xor(a[i], 16);
        a[i] += __shfl_xor(a[i], 32);
    }
    if (sub == 0) {
        float inv = 1.0f / fmaxf((float)(end - start), 1.0f);
        union { ushort u[16]; uint4 v[2]; } o;
#pragma unroll
        for (int i = 0; i < 16; i++) o.u[i] = f2bf(a[i] * inv);
        uint4* dst = (uint4*)(agg + (size_t)wid * 128 + l8 * 16);
        dst[0] = o.v[0];
        dst[1] = o.v[1];
    }
}

// ---------- MLP head + log_softmax: one block per graph ----------
__global__ __launch_bounds__(256) void final_kernel(const float* __restrict__ pooled,
                                                    const ushort* __restrict__ small,
                                                    void* __restrict__ out, int G,
                                                    const int* __restrict__ flag) {
    __shared__ float P[128];
    __shared__ float Thalf[128];
    __shared__ float T[128];
    __shared__ float R0[128], R1[128];
    const ushort* w1 = small + 512;
    const ushort* b1 = small + 16896;
    const ushort* w2 = small + 17024;
    const ushort* b2 = small + 17280;
    int g = blockIdx.x;
    int t = threadIdx.x;
    int j = t & 127, half = t >> 7;
    if (t < 128) P[t] = pooled[g * 128 + t];
    __syncthreads();
    float acc = 0.f;
    int k0 = half * 64;
#pragma unroll 8
    for (int k = k0; k < k0 + 64; k++) acc += P[k] * bf2f(w1[k * 128 + j]);
    if (half == 0) Thalf[j] = acc;
    __syncthreads();
    if (half == 1) T[j] = Thalf[j] + acc + bf2f(b1[j]);
    __syncthreads();
    if (t < 128) {
        float tv = T[t];
        R0[t] = tv * bf2f(w2[t * 2]);
        R1[t] = tv * bf2f(w2[t * 2 + 1]);
    }
    __syncthreads();
    for (int o = 64; o; o >>= 1) {
        if (t < o) { R0[t] += R0[t + o]; R1[t] += R1[t + o]; }
        __syncthreads();
    }
    if (t == 0) {
        float z0 = R0[0] + bf2f(b2[0]);
        float z1 = R1[0] + bf2f(b2[1]);
        float m = fmaxf(z0, z1);
        float l = m + logf(expf(z0 - m) + expf(z1 - m));
        float o0 = z0 - l, o1 = z1 - l;
        if (*flag) {
            ((float*)out)[2 * g]     = o0;
            ((float*)out)[2 * g + 1] = o1;
        } else {
            ((ushort*)out)[2 * g]     = f2bf(o0);
            ((ushort*)out)[2 * g + 1] = f2bf(o1);
        }
    }
}

extern "C" void kernel_launch(void* const* d_in, const int* in_sizes, int n_in,
                              void* d_out, int out_size, void* d_ws, size_t ws_size,
                              hipStream_t stream) {
    const void* x      = d_in[0];
    const int*  ei     = (const int*)d_in[1];
    const int*  batch  = (const int*)d_in[2];

    const int N = in_sizes[0] / 128;   // 50000 nodes
    const int E = in_sizes[1] / 2;     // 600000 edges
    const int G = out_size / 2;        // 64 graphs
    const int* srcIdx = ei;
    const int* dstIdx = ei + E;

    char* ws = (char*)d_ws;
    size_t off = 0;
    auto alloc = [&](size_t bytes) -> void* {
        off = (off + 255) & ~(size_t)255;
        void* p = ws + off;
        off += bytes;
        return p;
    };
    int*    flag    = (int*)alloc(4);
    int*    deg     = (int*)alloc((size_t)N * 4);
    int*    rowptr  = (int*)alloc((size_t)(N + 1) * 4);
    int*    cursor  = (int*)alloc((size_t)N * 4);
    int*    csr_src = (int*)alloc((size_t)E * 4);
    int*    csums   = (int*)alloc(((size_t)N / SCAN_CHUNK + 2) * 4);
    ushort* Wt0     = (ushort*)alloc(128 * 128 * 2);
    ushort* WtA0    = (ushort*)alloc(256 * 128 * 2);
    ushort* Wt1     = (ushort*)alloc(128 * 128 * 2);
    ushort* WtA1    = (ushort*)alloc(256 * 128 * 2);
    ushort* small   = (ushort*)alloc(17282 * 2);
    ushort* xb      = (ushort*)alloc((size_t)N * 128 * 2);
    ushort* msg     = (ushort*)alloc((size_t)N * 128 * 2);
    ushort* agg     = (ushort*)alloc((size_t)N * 128 * 2);
    ushort* h0      = (ushort*)alloc((size_t)N * 128 * 2);
    int*    pooled  = (int*)alloc((size_t)G * 128 * 4);

    // phase A: sniff (per-block) + convert x + weight prep + zero deg/pooled
    SmallSrcs ss;
    ss.p[0] = d_in[4];  ss.p[1] = d_in[6];  ss.p[2] = d_in[8];  ss.p[3] = d_in[10];
    ss.p[4] = d_in[11]; ss.p[5] = d_in[12]; ss.p[6] = d_in[13]; ss.p[7] = d_in[14];
    int nbconv = (N * 128 + 2047) / 2048;
    int nbzero = ((N / 4 + 1 + G * 32) + 255) / 256;
    phaseA<<<nbconv + 452 + nbzero, 256, 0, stream>>>(
        x, xb, N * 128, nbconv,
        d_in[3], d_in[5], d_in[7], d_in[9],
        Wt0, WtA0, Wt1, WtA1, ss, small, deg, pooled, N, G, flag);

    int gb = (N + 127) / 128;
    int ab = (N + 3) / 4;
    int eb = (E + 255) / 256;

    // layer-0 lin GEMM (independent of CSR)
    gemm_kernel<1, false, false, false><<<gb, 256, 0, stream>>>(
        xb, xb, Wt0, small + 0, msg, N, nullptr, nullptr, nullptr, nullptr, nullptr);

    // CSR build
    count_deg<<<eb, 256, 0, stream>>>(dstIdx, deg, E);
    int nchunks = (N + SCAN_CHUNK - 1) / SCAN_CHUNK;
    chunk_sum_kernel<<<nchunks, 256, 0, stream>>>(deg, csums, N);
    scan_phase2<<<N / SCAN_CHUNK + 1, 256, 0, stream>>>(deg, csums, rowptr, cursor, N);
    fill_kernel<<<eb, 256, 0, stream>>>(srcIdx, dstIdx, cursor, csr_src, E);

    // layer 0 aggregate + fused (upd0 -> h0) + (lin1 -> msg)
    aggregate_kernel<<<ab, 256, 0, stream>>>(msg, rowptr, csr_src, agg, N);
    gemm_kernel<2, true, false, true><<<gb, 256, 0, stream>>>(
        agg, xb, WtA0, small + 128, h0, N, nullptr, nullptr, Wt1, small + 256, msg);

    // layer 1 aggregate + fused upd1+max-pool
    aggregate_kernel<<<ab, 256, 0, stream>>>(msg, rowptr, csr_src, agg, N);
    gemm_kernel<2, true, true, false><<<gb, 256, 0, stream>>>(
        agg, h0, WtA1, small + 384, nullptr, N, batch, pooled, nullptr, nullptr, nullptr);

    // head
    final_kernel<<<G, 256, 0, stream>>>((const float*)pooled, small, d_out, G, flag);
}

// Round 10
// 267.662 us; speedup vs baseline: 1.0794x; 1.0507x over previous
//
#include <hip/hip_runtime.h>

// ---------- bf16 helpers (raw ushort representation) ----------
__device__ __forceinline__ float bf2f(ushort u) {
    union { uint i; float f; } c; c.i = ((uint)u) << 16; return c.f;
}
__device__ __forceinline__ float bf2lo(uint v) {
    union { uint i; float f; } c; c.i = v << 16; return c.f;
}
__device__ __forceinline__ float bf2hi(uint v) {
    union { uint i; float f; } c; c.i = v & 0xffff0000u; return c.f;
}
__device__ __forceinline__ ushort f2bf(float f) {
    union { float f; uint i; } c; c.f = f;
    uint b = c.i;
    uint r = (b + 0x7fffu + ((b >> 16) & 1u)) >> 16;
    return (ushort)r;
}

typedef __bf16 v8bf __attribute__((ext_vector_type(8)));
typedef float  v4f  __attribute__((ext_vector_type(4)));

__device__ __forceinline__ ushort load_conv(const void* src, int i, int isf32) {
    return isf32 ? f2bf(((const float*)src)[i]) : ((const ushort*)src)[i];
}

// ---------- phase A: per-block dtype sniff + weight prep + zero deg/pooled ----------
struct SmallSrcs { const void* p[8]; };
// small offsets: lin_b0 0, agg_b0 128, lin_b1 256, agg_b1 384, mp_w1 512, mp_b1 16896, mp_w2 17024, mp_b2 17280 (end 17282)
__global__ __launch_bounds__(256) void phaseA(
    const void* __restrict__ x,
    const void* __restrict__ w0, const void* __restrict__ wa0,
    const void* __restrict__ w1, const void* __restrict__ wa1,
    ushort* __restrict__ t0, ushort* __restrict__ ta0,
    ushort* __restrict__ t1, ushort* __restrict__ ta1,
    SmallSrcs s, ushort* __restrict__ smalldst,
    int* __restrict__ deg, int* __restrict__ pooled, int N, int G,
    int* __restrict__ flagOut) {
    __shared__ int sred[256];
    int b = blockIdx.x, t = threadIdx.x;
    // per-block sniff: f32 data -> low u16 decoded as bf16 has wild exponent ~44% of the time
    {
        const uint* words = (const uint*)x;
        int bad = 0;
        for (int i = t; i < 2048; i += 256) {
            uint w = words[i];
            uint exp = (w >> 7) & 0xffu;
            if (exp >= 143u) bad++;
        }
        sred[t] = bad;
        __syncthreads();
        for (int o = 128; o; o >>= 1) {
            if (t < o) sred[t] += sred[t + o];
            __syncthreads();
        }
    }
    const int isf = sred[0] > 64 ? 1 : 0;
    if (b == 0 && t == 0) *flagOut = isf;

    if (b < 452) {
        int idx = b * 256 + t;   // 0 .. 115585
        if (idx < 98304) {
            const void* W; ushort* T; int K; int local;
            if (idx < 16384)      { W = w0;  T = t0;  K = 128; local = idx; }
            else if (idx < 49152) { W = wa0; T = ta0; K = 256; local = idx - 16384; }
            else if (idx < 65536) { W = w1;  T = t1;  K = 128; local = idx - 49152; }
            else                  { W = wa1; T = ta1; K = 256; local = idx - 65536; }
            ushort v = load_conv(W, local, isf);
            int k = local >> 7;       // row in W
            int n = local & 127;      // col in W
            T[(size_t)n * K + k] = v;
        } else {
            int si = idx - 98304;
            if (si < 17282) {
                const int offs[9] = {0, 128, 256, 384, 512, 16896, 17024, 17280, 17282};
                int seg = 0;
                while (si >= offs[seg + 1]) seg++;
                smalldst[si] = load_conv(s.p[seg], si - offs[seg], isf);
            }
        }
    } else {
        int idx = (b - 452) * 256 + t;
        int nd4 = N >> 2;
        int4 z = {0, 0, 0, 0};
        if (idx < nd4) ((int4*)deg)[idx] = z;
        else if (idx == nd4) { for (int i = nd4 * 4; i < N; i++) deg[i] = 0; }
        else if (idx - nd4 - 1 < G * 32) ((int4*)pooled)[idx - nd4 - 1] = z;
    }
}

// ---------- CSR build ----------
__global__ __launch_bounds__(256) void count_deg(const int* __restrict__ dst, int* __restrict__ deg, int E) {
    int i = blockIdx.x * 256 + threadIdx.x;
    if (i < E) atomicAdd(&deg[dst[i]], 1);
}

#define SCAN_CHUNK 1024

__global__ __launch_bounds__(256) void chunk_sum_kernel(const int* __restrict__ deg,
                                                        int* __restrict__ csums, int n) {
    __shared__ int s[256];
    int t = threadIdx.x;
    int base = blockIdx.x * SCAN_CHUNK + t * 4;
    int v = 0;
    if (base + 4 <= n) {
        int4 q = *(const int4*)(deg + base);
        v = q.x + q.y + q.z + q.w;
    } else {
        for (int i = base; i < n; i++) v += deg[i];
    }
    s[t] = v;
    __syncthreads();
    for (int o = 128; o; o >>= 1) {
        if (t < o) s[t] += s[t + o];
        __syncthreads();
    }
    if (t == 0) csums[blockIdx.x] = s[0];
}

__global__ __launch_bounds__(256) void scan_phase2(const int* __restrict__ deg,
                                                   const int* __restrict__ csums,
                                                   int* __restrict__ rowptr, int* __restrict__ cursor,
                                                   int n) {
    __shared__ int red[256];
    int t = threadIdx.x, b = blockIdx.x;
    int v = 0;
    for (int i = t; i < b; i += 256) v += csums[i];
    red[t] = v;
    __syncthreads();
    for (int o = 128; o; o >>= 1) {
        if (t < o) red[t] += red[t + o];
        __syncthreads();
    }
    int chunkOff = red[0];
    __syncthreads();
    int base = b * SCAN_CHUNK + t * 4;
    int d0 = 0, d1 = 0, d2 = 0, d3 = 0;
    if (base + 4 <= n) {
        int4 q = *(const int4*)(deg + base);
        d0 = q.x; d1 = q.y; d2 = q.z; d3 = q.w;
    } else {
        if (base < n)     d0 = deg[base];
        if (base + 1 < n) d1 = deg[base + 1];
        if (base + 2 < n) d2 = deg[base + 2];
        if (base + 3 < n) d3 = deg[base + 3];
    }
    int s4 = d0 + d1 + d2 + d3;
    red[t] = s4;
    __syncthreads();
    for (int o = 1; o < 256; o <<= 1) {
        int u = (t >= o) ? red[t - o] : 0;
        __syncthreads();
        red[t] += u;
        __syncthreads();
    }
    int run = chunkOff + red[t] - s4;  // exclusive prefix at base
    if (base < n)     { rowptr[base]     = run; cursor[base]     = run; run += d0; }
    if (base + 1 < n) { rowptr[base + 1] = run; cursor[base + 1] = run; run += d1; }
    if (base + 2 < n) { rowptr[base + 2] = run; cursor[base + 2] = run; run += d2; }
    if (base + 3 < n) { rowptr[base + 3] = run; cursor[base + 3] = run; run += d3; }
    if (n >= base && n < base + 4) rowptr[n] = run;  // exactly one thread grid-wide
}

__global__ __launch_bounds__(256) void fill_kernel(const int* __restrict__ src, const int* __restrict__ dst,
                                                   int* __restrict__ cursor, int* __restrict__ csr_src, int E) {
    int i = blockIdx.x * 256 + threadIdx.x;
    if (i < E) {
        int pos = atomicAdd(&cursor[dst[i]], 1);
        csr_src[pos] = src[i];
    }
}

// ---------- MFMA GEMM, full-128-K staging per round ----------
// C = relu(A @ Bt^T + bias) [+ row-L2-normalize if NORM]
//   POOL: fused segment-max into pooled (no C store)
//   FUSE: after phase 1, Mout = relu(H @ Bt2^T + bias2) with H kept in LDS
//   CONV0/CONV1: A0/A1 may be f32 (per runtime flag) -> inline f2bf convert during staging
template <int NSTAGE, bool NORM, bool POOL, bool FUSE, bool CONV0, bool CONV1>
__global__ __launch_bounds__(256) void gemm_kernel(
    const void* __restrict__ A0, const void* __restrict__ A1,
    const ushort* __restrict__ Bt, const ushort* __restrict__ bias,
    ushort* __restrict__ Cout, int M,
    const int* __restrict__ batchv, int* __restrict__ pooled,
    const ushort* __restrict__ Bt2, const ushort* __restrict__ bias2,
    ushort* __restrict__ Mout, const int* __restrict__ flagp) {
    __shared__ __bf16 AsT[128 * 136];   // 34.8 KB  (reused as H tile in FUSE phase 2)
    __shared__ __bf16 BsT[128 * 136];   // 34.8 KB  (reused as Bt2 tile in FUSE phase 2)
    __shared__ int PoolLoc[POOL ? 8 * 128 : 1];
    const int t = threadIdx.x;
    const int w = t >> 6, lane = t & 63, ln = lane & 15, q = lane >> 4;
    const int blockRow = blockIdx.x * 128;
    const int K = NSTAGE * 128;
    const int isf = (CONV0 || CONV1) ? *flagp : 0;

    if (POOL) {
        for (int i = t; i < 8 * 128; i += 256) PoolLoc[i] = 0;
    }

    v4f acc[2][8];
#pragma unroll
    for (int i = 0; i < 2; i++)
#pragma unroll
        for (int j = 0; j < 8; j++) acc[i][j] = (v4f){0.f, 0.f, 0.f, 0.f};

#pragma unroll
    for (int st = 0; st < NSTAGE; st++) {
        const void* Ap = st ? A1 : A0;
        const bool cv = (st ? CONV1 : CONV0) && isf;
#pragma unroll
        for (int i = 0; i < 8; i++) {
            int c = i * 256 + t;
            int row = c >> 4, k8 = (c & 15) * 8;
            int grow = blockRow + row; if (grow >= M) grow = M - 1;
            uint4 av;
            if (cv) {
                const float* xf = (const float*)Ap + (size_t)grow * 128 + k8;
                float4 f0 = *(const float4*)xf;
                float4 f1 = *(const float4*)(xf + 4);
                union { ushort u[8]; uint4 v; } o;
                o.u[0] = f2bf(f0.x); o.u[1] = f2bf(f0.y); o.u[2] = f2bf(f0.z); o.u[3] = f2bf(f0.w);
                o.u[4] = f2bf(f1.x); o.u[5] = f2bf(f1.y); o.u[6] = f2bf(f1.z); o.u[7] = f2bf(f1.w);
                av = o.v;
            } else {
                av = *(const uint4*)((const ushort*)Ap + (size_t)grow * 128 + k8);
            }
            *(uint4*)&AsT[row * 136 + k8] = av;
            *(uint4*)&BsT[row * 136 + k8] = *(const uint4*)(Bt + (size_t)row * K + st * 128 + k8);
        }
        __syncthreads();
#pragma unroll
        for (int k0 = 0; k0 < 128; k0 += 32) {
            v8bf a0 = *(const v8bf*)&AsT[(w * 32 + ln) * 136 + k0 + q * 8];
            v8bf a1 = *(const v8bf*)&AsT[(w * 32 + 16 + ln) * 136 + k0 + q * 8];
#pragma unroll
            for (int nt = 0; nt < 8; nt++) {
                v8bf b = *(const v8bf*)&BsT[(nt * 16 + ln) * 136 + k0 + q * 8];
                acc[0][nt] = __builtin_amdgcn_mfma_f32_16x16x32_bf16(a0, b, acc[0][nt], 0, 0, 0);
                acc[1][nt] = __builtin_amdgcn_mfma_f32_16x16x32_bf16(a1, b, acc[1][nt], 0, 0, 0);
            }
        }
        __syncthreads();
    }

    float biasf[8];
#pragma unroll
    for (int nt = 0; nt < 8; nt++) biasf[nt] = bf2f(bias[nt * 16 + ln]);

    const int minB = POOL ? batchv[blockRow < M ? blockRow : M - 1] : 0;
    ushort* HsU = (ushort*)AsT;   // FUSE phase-2 A tile (128 x 136); safe: phase-1 staging done

#pragma unroll
    for (int mt = 0; mt < 2; mt++) {
        float v[8][4];
#pragma unroll
        for (int nt = 0; nt < 8; nt++)
#pragma unroll
            for (int r = 0; r < 4; r++) {
                float x = acc[mt][nt][r] + biasf[nt];
                v[nt][r] = x > 0.f ? x : 0.f;
            }
        float inv[4];
        if (NORM) {
#pragma unroll
            for (int r = 0; r < 4; r++) {
                float p = 0.f;
#pragma unroll
                for (int nt = 0; nt < 8; nt++) p += v[nt][r] * v[nt][r];
                p += __shfl_xor(p, 1);
                p += __shfl_xor(p, 2);
                p += __shfl_xor(p, 4);
                p += __shfl_xor(p, 8);
                inv[r] = 1.0f / fmaxf(sqrtf(p), 1e-12f);
            }
        }
        int rowloc = w * 32 + mt * 16 + q * 4;
#pragma unroll
        for (int r = 0; r < 4; r++) {
            int grow = blockRow + rowloc + r;
            if (POOL) {
                if (grow < M) {
                    int b = batchv[grow];
                    int rel = b - minB;
#pragma unroll
                    for (int nt = 0; nt < 8; nt++) {
                        float x = v[nt][r] * inv[r];
                        int xi = __float_as_int(x);
                        if (rel < 8) atomicMax(&PoolLoc[rel * 128 + nt * 16 + ln], xi);
                        else         atomicMax(&pooled[b * 128 + nt * 16 + ln], xi);
                    }
                }
            } else {
#pragma unroll
                for (int nt = 0; nt < 8; nt++) {
                    float x = NORM ? v[nt][r] * inv[r] : v[nt][r];
                    ushort xb = f2bf(x);
                    if (grow < M) Cout[(size_t)grow * 128 + nt * 16 + ln] = xb;
                    if (FUSE) HsU[(rowloc + r) * 136 + nt * 16 + ln] = xb;
                }
            }
        }
    }

    if (POOL) {
        __syncthreads();
        int lastRow = blockRow + 127; if (lastRow >= M) lastRow = M - 1;
        int span = batchv[lastRow] - minB + 1;
        if (span > 8) span = 8;
        for (int i = t; i < span * 128; i += 256) {
            int vv = PoolLoc[i];
            if (vv != 0) atomicMax(&pooled[(minB + (i >> 7)) * 128 + (i & 127)], vv);
        }
    }

    if (FUSE) {
        // phase 2: Mout = relu(H @ Bt2^T + bias2); H in AsT, Bt2 staged fully into BsT
#pragma unroll
        for (int i = 0; i < 8; i++) {
            int c = i * 256 + t;
            int row = c >> 4, k8 = (c & 15) * 8;
            *(uint4*)&BsT[row * 136 + k8] = *(const uint4*)(Bt2 + (size_t)row * 128 + k8);
        }
        __syncthreads();

        v4f acc2[2][8];
#pragma unroll
        for (int i = 0; i < 2; i++)
#pragma unroll
            for (int j = 0; j < 8; j++) acc2[i][j] = (v4f){0.f, 0.f, 0.f, 0.f};

#pragma unroll
        for (int k0 = 0; k0 < 128; k0 += 32) {
            v8bf a0 = *(const v8bf*)&AsT[(w * 32 + ln) * 136 + k0 + q * 8];
            v8bf a1 = *(const v8bf*)&AsT[(w * 32 + 16 + ln) * 136 + k0 + q * 8];
#pragma unroll
            for (int nt = 0; nt < 8; nt++) {
                v8bf b = *(const v8bf*)&BsT[(nt * 16 + ln) * 136 + k0 + q * 8];
                acc2[0][nt] = __builtin_amdgcn_mfma_f32_16x16x32_bf16(a0, b, acc2[0][nt], 0, 0, 0);
                acc2[1][nt] = __builtin_amdgcn_mfma_f32_16x16x32_bf16(a1, b, acc2[1][nt], 0, 0, 0);
            }
        }

        float biasf2[8];
#pragma unroll
        for (int nt = 0; nt < 8; nt++) biasf2[nt] = bf2f(bias2[nt * 16 + ln]);
#pragma unroll
        for (int mt = 0; mt < 2; mt++) {
            int rowbase = blockRow + w * 32 + mt * 16 + q * 4;
#pragma unroll
            for (int r = 0; r < 4; r++) {
                int grow = rowbase + r;
                if (grow < M) {
#pragma unroll
                    for (int nt = 0; nt < 8; nt++) {
                        float x = acc2[mt][nt][r] + biasf2[nt];
                        Mout[(size_t)grow * 128 + nt * 16 + ln] = f2bf(x > 0.f ? x : 0.f);
                    }
                }
            }
        }
    }
}

// ---------- CSR mean-aggregate: 4 edges in flight per wave, 16B/lane (measured optimum) ----------
__global__ __launch_bounds__(256) void aggregate_kernel(
    const ushort* __restrict__ msg, const int* __restrict__ rowptr,
    const int* __restrict__ csr_src, ushort* __restrict__ agg, int n) {
    int wid = (int)((blockIdx.x * 256u + threadIdx.x) >> 6);
    int lane = threadIdx.x & 63;
    int sub = lane >> 4;       // which of 4 concurrent edges
    int l16 = lane & 15;       // 16 lanes x 8 bf16 (16B) cover a 256B row
    if (wid >= n) return;
    int start = rowptr[wid], end = rowptr[wid + 1];
    float a[8] = {0.f, 0.f, 0.f, 0.f, 0.f, 0.f, 0.f, 0.f};
#pragma unroll 2
    for (int j = start + sub; j < end; j += 4) {
        int s = csr_src[j];
        uint4 v = *(const uint4*)(msg + (size_t)s * 128 + l16 * 8);
        a[0] += bf2lo(v.x); a[1] += bf2hi(v.x);
        a[2] += bf2lo(v.y); a[3] += bf2hi(v.y);
        a[4] += bf2lo(v.z); a[5] += bf2hi(v.z);
        a[6] += bf2lo(v.w); a[7] += bf2hi(v.w);
    }
#pragma unroll
    for (int i = 0; i < 8; i++) {
        a[i] += __shfl_xor(a[i], 16);
        a[i] += __shfl_xor(a[i], 32);
    }
    if (sub == 0) {
        float inv = 1.0f / fmaxf((float)(end - start), 1.0f);
        union { ushort u[8]; uint4 v; } o;
#pragma unroll
        for (int i = 0; i < 8; i++) o.u[i] = f2bf(a[i] * inv);
        *(uint4*)(agg + (size_t)wid * 128 + l16 * 8) = o.v;
    }
}

// ---------- MLP head + log_softmax: one block per graph ----------
__global__ __launch_bounds__(256) void final_kernel(const float* __restrict__ pooled,
                                                    const ushort* __restrict__ small,
                                                    void* __restrict__ out, int G,
                                                    const int* __restrict__ flag) {
    __shared__ float P[128];
    __shared__ float Thalf[128];
    __shared__ float T[128];
    __shared__ float R0[128], R1[128];
    const ushort* w1 = small + 512;
    const ushort* b1 = small + 16896;
    const ushort* w2 = small + 17024;
    const ushort* b2 = small + 17280;
    int g = blockIdx.x;
    int t = threadIdx.x;
    int j = t & 127, half = t >> 7;
    if (t < 128) P[t] = pooled[g * 128 + t];
    __syncthreads();
    float acc = 0.f;
    int k0 = half * 64;
#pragma unroll 8
    for (int k = k0; k < k0 + 64; k++) acc += P[k] * bf2f(w1[k * 128 + j]);
    if (half == 0) Thalf[j] = acc;
    __syncthreads();
    if (half == 1) T[j] = Thalf[j] + acc + bf2f(b1[j]);
    __syncthreads();
    if (t < 128) {
        float tv = T[t];
        R0[t] = tv * bf2f(w2[t * 2]);
        R1[t] = tv * bf2f(w2[t * 2 + 1]);
    }
    __syncthreads();
    for (int o = 64; o; o >>= 1) {
        if (t < o) { R0[t] += R0[t + o]; R1[t] += R1[t + o]; }
        __syncthreads();
    }
    if (t == 0) {
        float z0 = R0[0] + bf2f(b2[0]);
        float z1 = R1[0] + bf2f(b2[1]);
        float m = fmaxf(z0, z1);
        float l = m + logf(expf(z0 - m) + expf(z1 - m));
        float o0 = z0 - l, o1 = z1 - l;
        if (*flag) {
            ((float*)out)[2 * g]     = o0;
            ((float*)out)[2 * g + 1] = o1;
        } else {
            ((ushort*)out)[2 * g]     = f2bf(o0);
            ((ushort*)out)[2 * g + 1] = f2bf(o1);
        }
    }
}

extern "C" void kernel_launch(void* const* d_in, const int* in_sizes, int n_in,
                              void* d_out, int out_size, void* d_ws, size_t ws_size,
                              hipStream_t stream) {
    const void* x      = d_in[0];
    const int*  ei     = (const int*)d_in[1];
    const int*  batch  = (const int*)d_in[2];

    const int N = in_sizes[0] / 128;   // 50000 nodes
    const int E = in_sizes[1] / 2;     // 600000 edges
    const int G = out_size / 2;        // 64 graphs
    const int* srcIdx = ei;
    const int* dstIdx = ei + E;

    char* ws = (char*)d_ws;
    size_t off = 0;
    auto alloc = [&](size_t bytes) -> void* {
        off = (off + 255) & ~(size_t)255;
        void* p = ws + off;
        off += bytes;
        return p;
    };
    int*    flag    = (int*)alloc(4);
    int*    deg     = (int*)alloc((size_t)N * 4);
    int*    rowptr  = (int*)alloc((size_t)(N + 1) * 4);
    int*    cursor  = (int*)alloc((size_t)N * 4);
    int*    csr_src = (int*)alloc((size_t)E * 4);
    int*    csums   = (int*)alloc(((size_t)N / SCAN_CHUNK + 2) * 4);
    ushort* Wt0     = (ushort*)alloc(128 * 128 * 2);
    ushort* WtA0    = (ushort*)alloc(256 * 128 * 2);
    ushort* Wt1     = (ushort*)alloc(128 * 128 * 2);
    ushort* WtA1    = (ushort*)alloc(256 * 128 * 2);
    ushort* small   = (ushort*)alloc(17282 * 2);
    ushort* msg     = (ushort*)alloc((size_t)N * 128 * 2);
    ushort* agg     = (ushort*)alloc((size_t)N * 128 * 2);
    ushort* h0      = (ushort*)alloc((size_t)N * 128 * 2);
    int*    pooled  = (int*)alloc((size_t)G * 128 * 4);

    // phase A: sniff (per-block) + weight prep + zero deg/pooled
    SmallSrcs ss;
    ss.p[0] = d_in[4];  ss.p[1] = d_in[6];  ss.p[2] = d_in[8];  ss.p[3] = d_in[10];
    ss.p[4] = d_in[11]; ss.p[5] = d_in[12]; ss.p[6] = d_in[13]; ss.p[7] = d_in[14];
    int nbzero = ((N / 4 + 1 + G * 32) + 255) / 256;
    phaseA<<<452 + nbzero, 256, 0, stream>>>(
        x,
        d_in[3], d_in[5], d_in[7], d_in[9],
        Wt0, WtA0, Wt1, WtA1, ss, small, deg, pooled, N, G, flag);

    int gb = (N + 127) / 128;
    int ab = (N + 3) / 4;
    int eb = (E + 255) / 256;

    // layer-0 lin GEMM (reads x directly, inline-converting if f32)
    gemm_kernel<1, false, false, false, true, false><<<gb, 256, 0, stream>>>(
        x, x, Wt0, small + 0, msg, N, nullptr, nullptr, nullptr, nullptr, nullptr, flag);

    // CSR build
    count_deg<<<eb, 256, 0, stream>>>(dstIdx, deg, E);
    int nchunks = (N + SCAN_CHUNK - 1) / SCAN_CHUNK;
    chunk_sum_kernel<<<nchunks, 256, 0, stream>>>(deg, csums, N);
    scan_phase2<<<N / SCAN_CHUNK + 1, 256, 0, stream>>>(deg, csums, rowptr, cursor, N);
    fill_kernel<<<eb, 256, 0, stream>>>(srcIdx, dstIdx, cursor, csr_src, E);

    // layer 0 aggregate + fused (upd0 -> h0) + (lin1 -> msg); stage-1 A = x (inline convert)
    aggregate_kernel<<<ab, 256, 0, stream>>>(msg, rowptr, csr_src, agg, N);
    gemm_kernel<2, true, false, true, false, true><<<gb, 256, 0, stream>>>(
        agg, x, WtA0, small + 128, h0, N, nullptr, nullptr, Wt1, small + 256, msg, flag);

    // layer 1 aggregate + fused upd1+max-pool
    aggregate_kernel<<<ab, 256, 0, stream>>>(msg, rowptr, csr_src, agg, N);
    gemm_kernel<2, true, true, false, false, false><<<gb, 256, 0, stream>>>(
        agg, h0, WtA1, small + 384, nullptr, N, batch, pooled, nullptr, nullptr, nullptr, flag);

    // head
    final_kernel<<<G, 256, 0, stream>>>((const float*)pooled, small, d_out, G, flag);
}